// Round 7
// baseline (131.534 us; speedup 1.0000x reference)
//
#include <hip/hip_runtime.h>

// ---------------------------------------------------------------------------
// Attention: y = softmax( (xWq^T)(xWk^T)^T / sqrt(128) ) (xWv^T)
// B=4, N=4096, H=OUT=128. fp32 I/O, bf16 MFMA compute.
//
// R13:
//  flash: R12 proved not-BW-bound (4x less traffic, same 52us) -- it is a
//  serial latency chain at 1 wave/SIMD (Occ 9.5%, ~3900cyc/iter vs ~700 of
//  work). Restore TLP at same traffic: 4 waves x 1 q-tile (64 q-rows/block),
//  4 key-splits, grid 1024 = 4 blocks/CU = 4 waves/SIMD; each SIMD gets 4
//  waves from 4 INDEPENDENT blocks (block waves are on different SIMDs).
//  VGPR<=128 by design (R9/R10 lesson): K via global_load_lds (no staging
//  regs, no ds_write phase), V in 4x16-reg batches (peak 48), rowsum as
//  scalar adds of bf16-rounded P (no ones-MFMA). comb sums 4 partials.
//  proj: byte-identical to R8.
// ---------------------------------------------------------------------------

typedef __bf16 bf16;
typedef __attribute__((ext_vector_type(8))) __bf16 bf16x8;
typedef __attribute__((ext_vector_type(4))) __bf16 bf16x4;
typedef __attribute__((ext_vector_type(4))) float f32x4;

#define MFMA16(a, b, c) __builtin_amdgcn_mfma_f32_16x16x32_bf16(a, b, c, 0, 0, 0)
#define SB0() __builtin_amdgcn_sched_barrier(0)

#if __has_builtin(__builtin_amdgcn_exp2f)
#define EXP2F(x) __builtin_amdgcn_exp2f(x)
#else
#define EXP2F(x) exp2f(x)
#endif

static constexpr int BATCH = 4;
static constexpr int N = 4096;
static constexpr int D = 128;
static constexpr int ROWS = BATCH * N;  // 16384
// fold 1/sqrt(128) and log2(e) into q so softmax is raw exp2
static constexpr float QSCALE = 0.088388347648318447f * 1.4426950408889634f;

__device__ inline bf16x8 ld8_f32_bf16(const float* __restrict__ p) {
    f32x4 a = *(const f32x4*)p;
    f32x4 b = *(const f32x4*)(p + 4);
    bf16x8 r;
    r[0] = (bf16)a[0]; r[1] = (bf16)a[1]; r[2] = (bf16)a[2]; r[3] = (bf16)a[3];
    r[4] = (bf16)b[0]; r[5] = (bf16)b[1]; r[6] = (bf16)b[2]; r[7] = (bf16)b[3];
    return r;
}

// async global->LDS, 16B/lane; LDS dest = wave-uniform base + lane*16
__device__ inline void g2lds16(const bf16* __restrict__ src_lane,
                               bf16* lds_base) {
    __builtin_amdgcn_global_load_lds(
        (const __attribute__((address_space(1))) void*)src_lane,
        (__attribute__((address_space(3))) void*)lds_base, 16, 0, 0);
}

// Fragment layouts (16x16x32 bf16; lane = quad*16 + l16):
//  qf/kf: (tile,row,d) -> ((tile*4 + (d>>5))*64 + ((d&31)>>3)*16 + row)*8 + (d&7)
//         => one 16-row tile = 2048 elements; fragment (tile,ks) is 512
//         contiguous elems (64 lanes x 16B) -> global_load_lds-compatible.
//  vf (kappa-permuted): fragment (g64, ot, m), lane (quad, o15), elem j holds
//     V[64*g64 + kappa][ot*16 + o15] with
//     kappa = 32*m + (j<4 ? quad*4 + j : 16 + quad*4 + (j-4))
//  This matches the per-lane register order of S^T = mfma(K,Q) after exp2:
//     lane (quad,l16) holds P[q=l16][k = nt*16 + quad*4 + rg]  (nt=2m+j/4, rg=j&3)

// ---------------------------------------------------------------------------
// proj_all: grid 768 x 256. Block = (phase, 64-token group); 4 waves, one
// 16-token tile each. Stage W[phase] coalesced into LDS fragments (one
// __syncthreads), MFMA, transpose C through per-wave scratch, store.
// ---------------------------------------------------------------------------
__global__ __launch_bounds__(256) void proj_all(const float* __restrict__ x,
                                                const float* __restrict__ Wq,
                                                const float* __restrict__ Wk,
                                                const float* __restrict__ Wv,
                                                bf16* __restrict__ qf,
                                                bf16* __restrict__ kf,
                                                bf16* __restrict__ vf) {
    __shared__ __attribute__((aligned(16))) bf16 Wl[D * D];     // 32 KB
    __shared__ __attribute__((aligned(16))) bf16 Scr[4][2560];  // 20 KB

    const int lane = threadIdx.x & 63;
    const int w = threadIdx.x >> 6;
    const int l16 = lane & 15;
    const int quad = lane >> 4;
    const int phase = (int)(blockIdx.x % 3u);   // 0=Q 1=K 2=V
    const int group = (int)(blockIdx.x / 3u);   // 0..255 = 64-token group
    const int tile = group * 4 + w;             // global 16-token tile
    const int tok0 = tile << 4;

    const float* __restrict__ W = (phase == 0) ? Wq : (phase == 1) ? Wk : Wv;

    // ---- stage W into LDS in fragment layout (coalesced fp32 reads) ----
    {
        const int r = threadIdx.x >> 1;
        const int c0 = (threadIdx.x & 1) * 64;
#pragma unroll
        for (int g = 0; g < 8; g++) {
            const int h = c0 + g * 8;
            bf16x8 v = ld8_f32_bf16(W + r * D + h);
            const int frag = (r >> 4) * 4 + (h >> 5);
            const int ln = ((h & 31) >> 3) * 16 + (r & 15);
            *(bf16x8*)&Wl[(frag * 64 + ln) * 8] = v;
        }
    }

    // x fragments (A layout; identical lane layout serves as B too)
    bf16x8 xa[4];
#pragma unroll
    for (int ks = 0; ks < 4; ks++)
        xa[ks] = ld8_f32_bf16(x + (size_t)(tok0 + l16) * D + ks * 32 + quad * 8);

    __syncthreads();

    bf16* __restrict__ T = Scr[w];

    if (phase < 2) {
        // ---- Q or K: A = x, B = W fragment ----
        bf16* __restrict__ outp = (phase == 0) ? qf : kf;
        const float scale = (phase == 0) ? QSCALE : 1.0f;
#pragma unroll
        for (int nt = 0; nt < 8; nt++) {
            f32x4 acc = {0.f, 0.f, 0.f, 0.f};
#pragma unroll
            for (int ks = 0; ks < 4; ks++) {
                bf16x8 bw = *(const bf16x8*)&Wl[((nt * 4 + ks) * 64 + lane) * 8];
                acc = MFMA16(xa[ks], bw, acc);
            }
            // C: row = token = quad*4+rg, col = n = nt*16+l16
#pragma unroll
            for (int rg = 0; rg < 4; rg++)
                T[(quad * 4 + rg) * 136 + nt * 16 + l16] = (bf16)(acc[rg] * scale);
        }
        // readback fragments (tok = l16), coalesced 1KB stores
#pragma unroll
        for (int ks = 0; ks < 4; ks++) {
            bf16x8 frag = *(const bf16x8*)&T[l16 * 136 + ks * 32 + quad * 8];
            *(bf16x8*)(outp + (((size_t)tile * 4 + ks) * 64 + lane) * 8) = frag;
        }
    } else {
        // ---- V: A = Wv fragment (row = o), B = x (col = token) ----
#pragma unroll
        for (int mt = 0; mt < 8; mt++) {
            f32x4 acc = {0.f, 0.f, 0.f, 0.f};
#pragma unroll
            for (int ks = 0; ks < 4; ks++) {
                bf16x8 aw = *(const bf16x8*)&Wl[((mt * 4 + ks) * 64 + lane) * 8];
                acc = MFMA16(aw, xa[ks], acc);
            }
            // C: row = o = mt*16+quad*4+rg, col = token = l16  ->  T[o][tok]
#pragma unroll
            for (int rg = 0; rg < 4; rg++)
                T[(mt * 16 + quad * 4 + rg) * 20 + l16] = (bf16)acc[rg];
        }
        const int g64 = tok0 >> 6;
        const int t4 = (tok0 >> 4) & 3;
        const int m = t4 >> 1;
        const int jh = t4 & 1;
#pragma unroll
        for (int ot = 0; ot < 8; ot++) {
            bf16x4 v4 = *(const bf16x4*)&T[(ot * 16 + l16) * 20 + quad * 4];
            *(bf16x4*)(vf + ((((size_t)g64 * 8 + ot) * 2 + m) * 64 + lane) * 8 +
                       jh * 4) = v4;
        }
    }
}

// ---------------------------------------------------------------------------
// flash: grid 1024 x 256 (4 waves x 1 q-tile). bid&15 -> (batch, split);
// bid>>4 = q-group within batch (64 rows). Each block owns keys
// [split*1024, +1024) = 16 iters of 64. K double-buffered in LDS via
// global_load_lds (async, no VGPRs); V from global in 4x16-reg batches,
// L1-shared across waves. 4 blocks/CU -> 4 independent waves/SIMD.
// Partials (O + rowsum) fp32 to workspace; comb finishes.
// ---------------------------------------------------------------------------
__global__ __launch_bounds__(256) __attribute__((amdgpu_waves_per_eu(4, 4)))
void flash(const bf16* __restrict__ qf,
           const bf16* __restrict__ kf,
           const bf16* __restrict__ vf,
           float* __restrict__ po,
           float* __restrict__ ps) {
    __shared__ __attribute__((aligned(16))) bf16 kbuf[2][8192];  // 2 x 16 KB

    const int lane = threadIdx.x & 63;
    const int w = threadIdx.x >> 6;  // wave = q-tile owner
    const int l16 = lane & 15;
    const int quad = lane >> 4;

    const int lo = blockIdx.x & 15;
    const int batch = lo >> 2;
    const int split = lo & 3;
    const int qgb = (int)(blockIdx.x >> 4);      // 0..63
    const int qtg = batch * 256 + qgb * 4 + w;   // this wave's q-tile

    bf16x8 aq[4];
#pragma unroll
    for (int ks = 0; ks < 4; ks++)
        aq[ks] = *(const bf16x8*)(qf + (((size_t)qtg * 4 + ks) * 64 + lane) * 8);

    f32x4 oacc[8];
#pragma unroll
    for (int i = 0; i < 8; i++) oacc[i] = (f32x4){0.f, 0.f, 0.f, 0.f};
    float rs = 0.f;

    const int kb0 = split * (N / 4);  // 1024 keys per block
    const size_t kfrag0 = (size_t)(batch * 256) * 2048;  // batch base in kf

    // ---- prologue: stage it=0 K tile (16 KB) into kbuf[0] ----
    {
        const size_t kt = kfrag0 + (size_t)(kb0 >> 4) * 2048;
#pragma unroll
        for (int c = 0; c < 4; c++)
            g2lds16(kf + kt + ((c * 4 + w) * 64 + lane) * 8,
                    &kbuf[0][(c * 4 + w) * 512]);
    }
    __syncthreads();

#pragma unroll 1
    for (int it = 0; it < 16; it++) {
        const int kb = kb0 + it * 64;
        const int cur = it & 1;
        const size_t g64v = (size_t)batch * 64 + (kb >> 6);
        const bf16* __restrict__ kcur = &kbuf[cur][0];

        // ---- stage next K tile into the other buffer (async, no regs) ----
        {
            const int itn = (it < 15) ? it + 1 : 15;
            const size_t ktn = kfrag0 + (size_t)((kb0 + itn * 64) >> 4) * 2048;
#pragma unroll
            for (int c = 0; c < 4; c++)
                g2lds16(kf + ktn + ((c * 4 + w) * 64 + lane) * 8,
                        &kbuf[cur ^ 1][(c * 4 + w) * 512]);
        }

        // ---- V batches A (ot 0,1) and B (ot 2,3): cover under QK ----
        bf16x8 bvA[2][2], bvB[2][2];
#pragma unroll
        for (int o2 = 0; o2 < 2; o2++)
#pragma unroll
            for (int m = 0; m < 2; m++) {
                bvA[o2][m] = *(const bf16x8*)(vf +
                    (((g64v * 8 + o2) * 2 + m) * 64 + lane) * 8);
                bvB[o2][m] = *(const bf16x8*)(vf +
                    (((g64v * 8 + o2 + 2) * 2 + m) * 64 + lane) * 8);
            }
        SB0();

        // ---- S^T = k.q'' with K from LDS ----
        f32x4 sv[4];
#pragma unroll
        for (int nt = 0; nt < 4; nt++) sv[nt] = (f32x4){0.f, 0.f, 0.f, 0.f};
        __builtin_amdgcn_s_setprio(1);
#pragma unroll
        for (int ks = 0; ks < 4; ks++)
#pragma unroll
            for (int nt = 0; nt < 4; nt++) {
                bf16x8 bk = *(const bf16x8*)(kcur + ((nt * 4 + ks) * 64 + lane) * 8);
                sv[nt] = MFMA16(bk, aq[ks], sv[nt]);
            }
        __builtin_amdgcn_s_setprio(0);
        SB0();

        // ---- V batch C (ot 4,5): overlaps exp2 ----
        bf16x8 bvC[2][2];
#pragma unroll
        for (int o2 = 0; o2 < 2; o2++)
#pragma unroll
            for (int m = 0; m < 2; m++)
                bvC[o2][m] = *(const bf16x8*)(vf +
                    (((g64v * 8 + o2 + 4) * 2 + m) * 64 + lane) * 8);

        // ---- P = exp2(S^T) in-register; rowsum of bf16-rounded P ----
        bf16x8 ap[2];
#pragma unroll
        for (int m = 0; m < 2; m++) {
            bf16x8 t;
#pragma unroll
            for (int j = 0; j < 4; j++) {
                t[j] = (bf16)EXP2F(sv[2 * m][j]);
                t[j + 4] = (bf16)EXP2F(sv[2 * m + 1][j]);
                rs += (float)t[j] + (float)t[j + 4];
            }
            ap[m] = t;
        }
        SB0();

        // ---- PV: O += P.V  (D: row=q=quad*4+rg, col=o) ----
        __builtin_amdgcn_s_setprio(1);
#pragma unroll
        for (int o2 = 0; o2 < 2; o2++)
#pragma unroll
            for (int m = 0; m < 2; m++)
                oacc[o2] = MFMA16(ap[m], bvA[o2][m], oacc[o2]);
        __builtin_amdgcn_s_setprio(0);

        // ---- V batch D (ot 6,7): overlaps PV(B,C) ----
        bf16x8 bvD[2][2];
#pragma unroll
        for (int o2 = 0; o2 < 2; o2++)
#pragma unroll
            for (int m = 0; m < 2; m++)
                bvD[o2][m] = *(const bf16x8*)(vf +
                    (((g64v * 8 + o2 + 6) * 2 + m) * 64 + lane) * 8);

        __builtin_amdgcn_s_setprio(1);
#pragma unroll
        for (int o2 = 0; o2 < 2; o2++)
#pragma unroll
            for (int m = 0; m < 2; m++) {
                oacc[o2 + 2] = MFMA16(ap[m], bvB[o2][m], oacc[o2 + 2]);
                oacc[o2 + 4] = MFMA16(ap[m], bvC[o2][m], oacc[o2 + 4]);
            }
#pragma unroll
        for (int o2 = 0; o2 < 2; o2++)
#pragma unroll
            for (int m = 0; m < 2; m++)
                oacc[o2 + 6] = MFMA16(ap[m], bvD[o2][m], oacc[o2 + 6]);
        __builtin_amdgcn_s_setprio(0);

        // barrier: drains vmcnt -> next K tile landed; all waves flip buffers
        __syncthreads();
    }

    // ---- rowsum: reduce the 4 quad-partials of each row q=l16 ----
    rs += __shfl_xor(rs, 16);
    rs += __shfl_xor(rs, 32);

    // ---- write fp32 partials ----
    const int row0 = qtg * 16;
    const size_t pbase = (size_t)split * ROWS * D;
#pragma unroll
    for (int rg = 0; rg < 4; rg++) {
        float* __restrict__ pr = po + pbase + (size_t)(row0 + quad * 4 + rg) * D;
#pragma unroll
        for (int t = 0; t < 8; t++) pr[t * 16 + l16] = oacc[t][rg];
    }
    if (quad == 0) ps[split * ROWS + row0 + l16] = rs;
}

// ---------------------------------------------------------------------------
// comb: y = (P0+P1+P2+P3) / (S0+S1+S2+S3). Grid 2048 x 256, float4/thread.
// ---------------------------------------------------------------------------
__global__ __launch_bounds__(256) void comb(const float* __restrict__ po,
                                            const float* __restrict__ ps,
                                            float* __restrict__ y) {
    const int idx = blockIdx.x * 256 + threadIdx.x;  // 0..524287
    const int row = idx >> 5;
    const int c4 = idx & 31;
    f32x4 acc = {0.f, 0.f, 0.f, 0.f};
    float den = 0.f;
#pragma unroll
    for (int s = 0; s < 4; s++) {
        const f32x4 a =
            *(const f32x4*)(po + (size_t)s * ROWS * D + (size_t)row * D + c4 * 4);
#pragma unroll
        for (int j = 0; j < 4; j++) acc[j] += a[j];
        den += ps[s * ROWS + row];
    }
    const float rl = 1.0f / den;
    f32x4 r;
#pragma unroll
    for (int j = 0; j < 4; j++) r[j] = acc[j] * rl;
    *(f32x4*)(y + (size_t)row * D + c4 * 4) = r;
}

// ---------------------------------------------------------------------------
extern "C" void kernel_launch(void* const* d_in, const int* in_sizes, int n_in,
                              void* d_out, int out_size, void* d_ws, size_t ws_size,
                              hipStream_t stream) {
    const float* x = (const float*)d_in[0];
    const float* Wq = (const float*)d_in[1];
    const float* Wk = (const float*)d_in[2];
    const float* Wv = (const float*)d_in[3];
    float* y = (float*)d_out;

    bf16* qf = (bf16*)d_ws;            // 4MB
    bf16* kf = qf + (size_t)ROWS * D;  // 4MB
    bf16* vf = kf + (size_t)ROWS * D;  // 4MB (kappa-permuted fragment layout)
    float* po = (float*)(vf + (size_t)ROWS * D);  // 4 x 8.39MB fp32 partials
    float* ps = po + 4 * (size_t)ROWS * D;        // 4 x 64KB rowsums

    proj_all<<<768, 256, 0, stream>>>(x, Wq, Wk, Wv, qf, kf, vf);
    flash<<<1024, 256, 0, stream>>>(qf, kf, vf, po, ps);
    comb<<<2048, 256, 0, stream>>>(po, ps, y);
}

// Round 8
// 124.203 us; speedup vs baseline: 1.0590x; 1.0590x over previous
//
#include <hip/hip_runtime.h>

// ---------------------------------------------------------------------------
// Attention: y = softmax( (xWq^T)(xWk^T)^T / sqrt(128) ) (xWv^T)
// B=4, N=4096, H=OUT=128. fp32 I/O, bf16 MFMA compute.
//
// R14:
//  flash: ledger R8/R12/R13 -> RF ingest of K+V (1.07GB @ 2qt/wave) through
//  the vector-mem path (~33B/cyc/CU) is the wall. Split it across ports:
//  grid 256 x 8 waves (1 block/CU, 2 waves/SIMD). Waves pair (w,w+4); pair p
//  = key-quarter p (1024 keys, 16 iters); each pair-wave owns 2 q-tiles
//  (block = 64 q-rows). K: per-pair dbuf LDS via global_load_lds (fill at
//  iter top; end-of-iter barrier drain lands it free) -> LDS port, L2 K
//  traffic halved. V: global->regs (R12 bv1/bv2 batching) -> TA port alone.
//  In-block 4-split combine through reused 128KB LDS kills the comb kernel
//  and the 35MB partial round-trip.
//  proj: byte-identical to R8.
// ---------------------------------------------------------------------------

typedef __bf16 bf16;
typedef __attribute__((ext_vector_type(8))) __bf16 bf16x8;
typedef __attribute__((ext_vector_type(4))) __bf16 bf16x4;
typedef __attribute__((ext_vector_type(4))) float f32x4;

#define MFMA16(a, b, c) __builtin_amdgcn_mfma_f32_16x16x32_bf16(a, b, c, 0, 0, 0)
#define SB0() __builtin_amdgcn_sched_barrier(0)

#if __has_builtin(__builtin_amdgcn_exp2f)
#define EXP2F(x) __builtin_amdgcn_exp2f(x)
#else
#define EXP2F(x) exp2f(x)
#endif

static constexpr int BATCH = 4;
static constexpr int N = 4096;
static constexpr int D = 128;
static constexpr int ROWS = BATCH * N;  // 16384
// fold 1/sqrt(128) and log2(e) into q so softmax is raw exp2
static constexpr float QSCALE = 0.088388347648318447f * 1.4426950408889634f;

__device__ inline bf16x8 ld8_f32_bf16(const float* __restrict__ p) {
    f32x4 a = *(const f32x4*)p;
    f32x4 b = *(const f32x4*)(p + 4);
    bf16x8 r;
    r[0] = (bf16)a[0]; r[1] = (bf16)a[1]; r[2] = (bf16)a[2]; r[3] = (bf16)a[3];
    r[4] = (bf16)b[0]; r[5] = (bf16)b[1]; r[6] = (bf16)b[2]; r[7] = (bf16)b[3];
    return r;
}

// async global->LDS, 16B/lane; LDS dest = wave-uniform base + lane*16
__device__ inline void g2lds16(const bf16* __restrict__ src_lane,
                               bf16* lds_base) {
    __builtin_amdgcn_global_load_lds(
        (const __attribute__((address_space(1))) void*)src_lane,
        (__attribute__((address_space(3))) void*)lds_base, 16, 0, 0);
}

// Fragment layouts (16x16x32 bf16; lane = quad*16 + l16):
//  qf/kf: (tile,row,d) -> ((tile*4 + (d>>5))*64 + ((d&31)>>3)*16 + row)*8 + (d&7)
//         => one 16-row tile = 2048 elements; a 64-key K tile = 16 units of
//         512 contiguous elems (64 lanes x 16B) -> global_load_lds-compatible.
//  vf (kappa-permuted): fragment (g64, ot, m), lane (quad, o15), elem j holds
//     V[64*g64 + kappa][ot*16 + o15] with
//     kappa = 32*m + (j<4 ? quad*4 + j : 16 + quad*4 + (j-4))
//  This matches the per-lane register order of S^T = mfma(K,Q) after exp2:
//     lane (quad,l16) holds P[q=l16][k = nt*16 + quad*4 + rg]  (nt=2m+j/4, rg=j&3)

// ---------------------------------------------------------------------------
// proj_all: grid 768 x 256. Block = (phase, 64-token group); 4 waves, one
// 16-token tile each. Stage W[phase] coalesced into LDS fragments (one
// __syncthreads), MFMA, transpose C through per-wave scratch, store.
// ---------------------------------------------------------------------------
__global__ __launch_bounds__(256) void proj_all(const float* __restrict__ x,
                                                const float* __restrict__ Wq,
                                                const float* __restrict__ Wk,
                                                const float* __restrict__ Wv,
                                                bf16* __restrict__ qf,
                                                bf16* __restrict__ kf,
                                                bf16* __restrict__ vf) {
    __shared__ __attribute__((aligned(16))) bf16 Wl[D * D];     // 32 KB
    __shared__ __attribute__((aligned(16))) bf16 Scr[4][2560];  // 20 KB

    const int lane = threadIdx.x & 63;
    const int w = threadIdx.x >> 6;
    const int l16 = lane & 15;
    const int quad = lane >> 4;
    const int phase = (int)(blockIdx.x % 3u);   // 0=Q 1=K 2=V
    const int group = (int)(blockIdx.x / 3u);   // 0..255 = 64-token group
    const int tile = group * 4 + w;             // global 16-token tile
    const int tok0 = tile << 4;

    const float* __restrict__ W = (phase == 0) ? Wq : (phase == 1) ? Wk : Wv;

    // ---- stage W into LDS in fragment layout (coalesced fp32 reads) ----
    {
        const int r = threadIdx.x >> 1;
        const int c0 = (threadIdx.x & 1) * 64;
#pragma unroll
        for (int g = 0; g < 8; g++) {
            const int h = c0 + g * 8;
            bf16x8 v = ld8_f32_bf16(W + r * D + h);
            const int frag = (r >> 4) * 4 + (h >> 5);
            const int ln = ((h & 31) >> 3) * 16 + (r & 15);
            *(bf16x8*)&Wl[(frag * 64 + ln) * 8] = v;
        }
    }

    // x fragments (A layout; identical lane layout serves as B too)
    bf16x8 xa[4];
#pragma unroll
    for (int ks = 0; ks < 4; ks++)
        xa[ks] = ld8_f32_bf16(x + (size_t)(tok0 + l16) * D + ks * 32 + quad * 8);

    __syncthreads();

    bf16* __restrict__ T = Scr[w];

    if (phase < 2) {
        // ---- Q or K: A = x, B = W fragment ----
        bf16* __restrict__ outp = (phase == 0) ? qf : kf;
        const float scale = (phase == 0) ? QSCALE : 1.0f;
#pragma unroll
        for (int nt = 0; nt < 8; nt++) {
            f32x4 acc = {0.f, 0.f, 0.f, 0.f};
#pragma unroll
            for (int ks = 0; ks < 4; ks++) {
                bf16x8 bw = *(const bf16x8*)&Wl[((nt * 4 + ks) * 64 + lane) * 8];
                acc = MFMA16(xa[ks], bw, acc);
            }
            // C: row = token = quad*4+rg, col = n = nt*16+l16
#pragma unroll
            for (int rg = 0; rg < 4; rg++)
                T[(quad * 4 + rg) * 136 + nt * 16 + l16] = (bf16)(acc[rg] * scale);
        }
        // readback fragments (tok = l16), coalesced 1KB stores
#pragma unroll
        for (int ks = 0; ks < 4; ks++) {
            bf16x8 frag = *(const bf16x8*)&T[l16 * 136 + ks * 32 + quad * 8];
            *(bf16x8*)(outp + (((size_t)tile * 4 + ks) * 64 + lane) * 8) = frag;
        }
    } else {
        // ---- V: A = Wv fragment (row = o), B = x (col = token) ----
#pragma unroll
        for (int mt = 0; mt < 8; mt++) {
            f32x4 acc = {0.f, 0.f, 0.f, 0.f};
#pragma unroll
            for (int ks = 0; ks < 4; ks++) {
                bf16x8 aw = *(const bf16x8*)&Wl[((mt * 4 + ks) * 64 + lane) * 8];
                acc = MFMA16(aw, xa[ks], acc);
            }
            // C: row = o = mt*16+quad*4+rg, col = token = l16  ->  T[o][tok]
#pragma unroll
            for (int rg = 0; rg < 4; rg++)
                T[(mt * 16 + quad * 4 + rg) * 20 + l16] = (bf16)acc[rg];
        }
        const int g64 = tok0 >> 6;
        const int t4 = (tok0 >> 4) & 3;
        const int m = t4 >> 1;
        const int jh = t4 & 1;
#pragma unroll
        for (int ot = 0; ot < 8; ot++) {
            bf16x4 v4 = *(const bf16x4*)&T[(ot * 16 + l16) * 20 + quad * 4];
            *(bf16x4*)(vf + ((((size_t)g64 * 8 + ot) * 2 + m) * 64 + lane) * 8 +
                       jh * 4) = v4;
        }
    }
}

// ---------------------------------------------------------------------------
// flash: grid 256 x 512 (8 waves, 1 block/CU, 2 waves/SIMD). Wave w ->
// (pair p = w&3, u = w>>2). Pair p owns keys [p*1024, +1024) (16 iters of
// 64); wave (p,u) owns q-tiles qtg0+2u, +1 (block = 64 q-rows). K: per-pair
// double-buffered LDS via global_load_lds; V: global->regs. End: 4-split
// combine through reused LDS, direct y write. No comb kernel.
// ---------------------------------------------------------------------------
__global__ __launch_bounds__(512) __attribute__((amdgpu_waves_per_eu(2, 2)))
void flash(const bf16* __restrict__ qf,
           const bf16* __restrict__ kf,
           const bf16* __restrict__ vf,
           float* __restrict__ out) {
    // loop: kbuf[pair][buf][16KB]; epilogue: reused as float Rs[12][16*148]
    __shared__ __attribute__((aligned(16))) bf16 kbuf[4][2][8192];  // 128 KB

    const int lane = threadIdx.x & 63;
    const int w = threadIdx.x >> 6;
    const int p = w & 3;    // key-quarter
    const int u = w >> 2;   // q-half within block
    const int l16 = lane & 15;
    const int quad = lane >> 4;

    // XCD swizzle: bid%8 -> (batch, sub); 2 XCDs per batch.
    const int lo = blockIdx.x & 7;
    const int batch = lo >> 1;
    const int sub = lo & 1;
    const int qg = (int)(blockIdx.x >> 3) * 2 + sub;  // 0..63
    const int qtg0 = batch * 256 + qg * 4;

    bf16x8 aq[2][4];
#pragma unroll
    for (int j = 0; j < 2; j++)
#pragma unroll
        for (int ks = 0; ks < 4; ks++)
            aq[j][ks] = *(const bf16x8*)(qf +
                (((size_t)(qtg0 + 2 * u + j) * 4 + ks) * 64 + lane) * 8);

    f32x4 oacc[2][9];
#pragma unroll
    for (int j = 0; j < 2; j++)
#pragma unroll
        for (int i = 0; i < 9; i++) oacc[j][i] = (f32x4){0.f, 0.f, 0.f, 0.f};

    bf16x8 vone;
#pragma unroll
    for (int j = 0; j < 8; j++) vone[j] = (bf16)1.0f;

    const int kb0 = p * 1024;  // this pair's key base
    const size_t kfb = (size_t)(batch * 256) * 2048;  // batch base in kf

    // ---- prologue: both pair-waves fill kbuf[p][0] (u covers 8 units) ----
    {
        const size_t kt0 = kfb + (size_t)(kb0 >> 4) * 2048;
#pragma unroll
        for (int c = 0; c < 8; c++) {
            const int unit = u * 8 + c;
            g2lds16(kf + kt0 + unit * 512 + lane * 8, &kbuf[p][0][unit * 512]);
        }
    }
    __syncthreads();

#pragma unroll 1
    for (int it = 0; it < 16; it++) {
        const int kb = kb0 + it * 64;
        const int cur = it & 1;
        const size_t g64v = (size_t)batch * 64 + (kb >> 6);
        const bf16* __restrict__ kcur = &kbuf[p][cur][0];

        // ---- fill next K tile (async; landed by end-of-iter barrier) ----
        {
            const int itn = (it < 15) ? it + 1 : 15;
            const size_t ktn = kfb + (size_t)((kb0 + itn * 64) >> 4) * 2048;
#pragma unroll
            for (int c = 0; c < 8; c++) {
                const int unit = u * 8 + c;
                g2lds16(kf + ktn + unit * 512 + lane * 8,
                        &kbuf[p][cur ^ 1][unit * 512]);
            }
        }

        // ---- V batch 1 (ot 0..3): covered under QK ----
        bf16x8 bv1[4][2];
#pragma unroll
        for (int ot = 0; ot < 4; ot++)
#pragma unroll
            for (int m = 0; m < 2; m++)
                bv1[ot][m] = *(const bf16x8*)(vf +
                    (((g64v * 8 + ot) * 2 + m) * 64 + lane) * 8);
        SB0();

        // ---- S^T = k.q'' with K fragments from LDS ----
        f32x4 sv[2][4];
#pragma unroll
        for (int j = 0; j < 2; j++)
#pragma unroll
            for (int nt = 0; nt < 4; nt++) sv[j][nt] = (f32x4){0.f, 0.f, 0.f, 0.f};
        __builtin_amdgcn_s_setprio(1);
#pragma unroll
        for (int ks = 0; ks < 4; ks++)
#pragma unroll
            for (int nt = 0; nt < 4; nt++) {
                bf16x8 bk = *(const bf16x8*)(kcur + ((nt * 4 + ks) * 64 + lane) * 8);
                sv[0][nt] = MFMA16(bk, aq[0][ks], sv[0][nt]);
                sv[1][nt] = MFMA16(bk, aq[1][ks], sv[1][nt]);
            }
        __builtin_amdgcn_s_setprio(0);
        SB0();

        // ---- V batch 2 (ot 4..7) ----
        bf16x8 bv2[4][2];
#pragma unroll
        for (int ot = 0; ot < 4; ot++)
#pragma unroll
            for (int m = 0; m < 2; m++)
                bv2[ot][m] = *(const bf16x8*)(vf +
                    (((g64v * 8 + ot + 4) * 2 + m) * 64 + lane) * 8);
        SB0();

        // ---- P = exp2(S^T) -> A-fragments, in-register ----
        bf16x8 ap[2][2];
#pragma unroll
        for (int j = 0; j < 2; j++)
#pragma unroll
            for (int m = 0; m < 2; m++) {
                bf16x8 t;
#pragma unroll
                for (int e = 0; e < 4; e++) {
                    t[e] = (bf16)EXP2F(sv[j][2 * m][e]);
                    t[e + 4] = (bf16)EXP2F(sv[j][2 * m + 1][e]);
                }
                ap[j][m] = t;
            }
        SB0();

        // ---- O += P.V ----
        __builtin_amdgcn_s_setprio(1);
#pragma unroll
        for (int ot = 0; ot < 4; ot++)
#pragma unroll
            for (int m = 0; m < 2; m++) {
                oacc[0][ot] = MFMA16(ap[0][m], bv1[ot][m], oacc[0][ot]);
                oacc[1][ot] = MFMA16(ap[1][m], bv1[ot][m], oacc[1][ot]);
            }
#pragma unroll
        for (int ot = 0; ot < 4; ot++)
#pragma unroll
            for (int m = 0; m < 2; m++) {
                oacc[0][ot + 4] = MFMA16(ap[0][m], bv2[ot][m], oacc[0][ot + 4]);
                oacc[1][ot + 4] = MFMA16(ap[1][m], bv2[ot][m], oacc[1][ot + 4]);
            }
#pragma unroll
        for (int j = 0; j < 2; j++)
#pragma unroll
            for (int m = 0; m < 2; m++)
                oacc[j][8] = MFMA16(ap[j][m], vone, oacc[j][8]);
        __builtin_amdgcn_s_setprio(0);

        // barrier: drains the async K fill; all pairs flip buffers together
        __syncthreads();
    }

    // ---- 4-split combine through reused LDS (12 tiles x 16x148 fp32) ----
    float* __restrict__ Rs = (float*)kbuf;
    if (p > 0) {
#pragma unroll
        for (int j = 0; j < 2; j++) {
            float* __restrict__ dst = Rs + ((p - 1) * 4 + u * 2 + j) * 2368;
#pragma unroll
            for (int t = 0; t < 9; t++)
#pragma unroll
                for (int rg = 0; rg < 4; rg++)
                    dst[(quad * 4 + rg) * 148 + t * 16 + l16] = oacc[j][t][rg];
        }
    }
    __syncthreads();
    if (p == 0) {
#pragma unroll
        for (int j = 0; j < 2; j++) {
#pragma unroll
            for (int sIdx = 0; sIdx < 3; sIdx++) {
                const float* __restrict__ src = Rs + (sIdx * 4 + u * 2 + j) * 2368;
#pragma unroll
                for (int t = 0; t < 9; t++)
#pragma unroll
                    for (int rg = 0; rg < 4; rg++)
                        oacc[j][t][rg] += src[(quad * 4 + rg) * 148 + t * 16 + l16];
            }
#pragma unroll
            for (int rg = 0; rg < 4; rg++) {
                const float rl = 1.0f / oacc[j][8][rg];
                float* __restrict__ yrow = out +
                    (((size_t)(qtg0 + 2 * u + j)) * 16 + quad * 4 + rg) * D;
#pragma unroll
                for (int t = 0; t < 8; t++)
                    yrow[t * 16 + l16] = oacc[j][t][rg] * rl;
            }
        }
    }
}

// ---------------------------------------------------------------------------
extern "C" void kernel_launch(void* const* d_in, const int* in_sizes, int n_in,
                              void* d_out, int out_size, void* d_ws, size_t ws_size,
                              hipStream_t stream) {
    const float* x = (const float*)d_in[0];
    const float* Wq = (const float*)d_in[1];
    const float* Wk = (const float*)d_in[2];
    const float* Wv = (const float*)d_in[3];
    float* y = (float*)d_out;

    bf16* qf = (bf16*)d_ws;            // 4MB
    bf16* kf = qf + (size_t)ROWS * D;  // 4MB
    bf16* vf = kf + (size_t)ROWS * D;  // 4MB (kappa-permuted fragment layout)

    proj_all<<<768, 256, 0, stream>>>(x, Wq, Wk, Wv, qf, kf, vf);
    flash<<<256, 512, 0, stream>>>(qf, kf, vf, y);
}

// Round 10
// 121.017 us; speedup vs baseline: 1.0869x; 1.0263x over previous
//
#include <hip/hip_runtime.h>

// ---------------------------------------------------------------------------
// Attention: y = softmax( (xWq^T)(xWk^T)^T / sqrt(128) ) (xWv^T)
// B=4, N=4096, H=OUT=128. fp32 I/O, bf16 MFMA compute.
//
// R16: R15 with the K-fill unit-count bug fixed. A 128-key tile = 16384
//  elems = 32 units of 512; each of the 2 pair-waves fills 16 units
//  (R15 issued 32 each = 64KB into a 32KB buffer, overrunning kbuf[p+1] ->
//  corrupted K, absmax 0.45). Fix: c<16, unit=u*16+c (prologue + loop).
//  Everything else identical to R15:
//  flash: 256 blocks x 8 waves; pair p = key-quarter (1024 keys, 8 iters of
//  128 = sub-groups A,B); wave (p,u) owns 2 q-tiles. K in per-pair
//  single-buffered 32KB LDS via global_load_lds (fill after reads-barrier,
//  landed by end-of-iter barrier); V global->regs one 64-key group at a
//  time; rowsum scalar+shfl; in-block 4-split combine. KBLK=128 halves the
//  per-step barrier/drain count vs R14 (theory: ~2800cyc/step overhead).
//  proj: byte-identical to R8.
// ---------------------------------------------------------------------------

typedef __bf16 bf16;
typedef __attribute__((ext_vector_type(8))) __bf16 bf16x8;
typedef __attribute__((ext_vector_type(4))) __bf16 bf16x4;
typedef __attribute__((ext_vector_type(4))) float f32x4;

#define MFMA16(a, b, c) __builtin_amdgcn_mfma_f32_16x16x32_bf16(a, b, c, 0, 0, 0)
#define SB0() __builtin_amdgcn_sched_barrier(0)

#if __has_builtin(__builtin_amdgcn_exp2f)
#define EXP2F(x) __builtin_amdgcn_exp2f(x)
#else
#define EXP2F(x) exp2f(x)
#endif

static constexpr int BATCH = 4;
static constexpr int N = 4096;
static constexpr int D = 128;
static constexpr int ROWS = BATCH * N;  // 16384
// fold 1/sqrt(128) and log2(e) into q so softmax is raw exp2
static constexpr float QSCALE = 0.088388347648318447f * 1.4426950408889634f;

__device__ inline bf16x8 ld8_f32_bf16(const float* __restrict__ p) {
    f32x4 a = *(const f32x4*)p;
    f32x4 b = *(const f32x4*)(p + 4);
    bf16x8 r;
    r[0] = (bf16)a[0]; r[1] = (bf16)a[1]; r[2] = (bf16)a[2]; r[3] = (bf16)a[3];
    r[4] = (bf16)b[0]; r[5] = (bf16)b[1]; r[6] = (bf16)b[2]; r[7] = (bf16)b[3];
    return r;
}

// async global->LDS, 16B/lane; LDS dest = wave-uniform base + lane*16
__device__ inline void g2lds16(const bf16* __restrict__ src_lane,
                               bf16* lds_base) {
    __builtin_amdgcn_global_load_lds(
        (const __attribute__((address_space(1))) void*)src_lane,
        (__attribute__((address_space(3))) void*)lds_base, 16, 0, 0);
}

// Fragment layouts (16x16x32 bf16; lane = quad*16 + l16):
//  qf/kf: (tile,row,d) -> ((tile*4 + (d>>5))*64 + ((d&31)>>3)*16 + row)*8 + (d&7)
//         => one 16-row tile = 2048 elements; a 128-key K tile = 16384 elems
//         = 32 units of 512 contiguous elems (64 lanes x 16B each).
//  vf (kappa-permuted): fragment (g64, ot, m), lane (quad, o15), elem j holds
//     V[64*g64 + kappa][ot*16 + o15] with
//     kappa = 32*m + (j<4 ? quad*4 + j : 16 + quad*4 + (j-4))
//  This matches the per-lane register order of S^T = mfma(K,Q) after exp2:
//     lane (quad,l16) holds P[q=l16][k = nt*16 + quad*4 + rg]  (nt=2m+j/4, rg=j&3)

// ---------------------------------------------------------------------------
// proj_all: grid 768 x 256. Block = (phase, 64-token group); 4 waves, one
// 16-token tile each. Stage W[phase] coalesced into LDS fragments (one
// __syncthreads), MFMA, transpose C through per-wave scratch, store.
// ---------------------------------------------------------------------------
__global__ __launch_bounds__(256) void proj_all(const float* __restrict__ x,
                                                const float* __restrict__ Wq,
                                                const float* __restrict__ Wk,
                                                const float* __restrict__ Wv,
                                                bf16* __restrict__ qf,
                                                bf16* __restrict__ kf,
                                                bf16* __restrict__ vf) {
    __shared__ __attribute__((aligned(16))) bf16 Wl[D * D];     // 32 KB
    __shared__ __attribute__((aligned(16))) bf16 Scr[4][2560];  // 20 KB

    const int lane = threadIdx.x & 63;
    const int w = threadIdx.x >> 6;
    const int l16 = lane & 15;
    const int quad = lane >> 4;
    const int phase = (int)(blockIdx.x % 3u);   // 0=Q 1=K 2=V
    const int group = (int)(blockIdx.x / 3u);   // 0..255 = 64-token group
    const int tile = group * 4 + w;             // global 16-token tile
    const int tok0 = tile << 4;

    const float* __restrict__ W = (phase == 0) ? Wq : (phase == 1) ? Wk : Wv;

    // ---- stage W into LDS in fragment layout (coalesced fp32 reads) ----
    {
        const int r = threadIdx.x >> 1;
        const int c0 = (threadIdx.x & 1) * 64;
#pragma unroll
        for (int g = 0; g < 8; g++) {
            const int h = c0 + g * 8;
            bf16x8 v = ld8_f32_bf16(W + r * D + h);
            const int frag = (r >> 4) * 4 + (h >> 5);
            const int ln = ((h & 31) >> 3) * 16 + (r & 15);
            *(bf16x8*)&Wl[(frag * 64 + ln) * 8] = v;
        }
    }

    // x fragments (A layout; identical lane layout serves as B too)
    bf16x8 xa[4];
#pragma unroll
    for (int ks = 0; ks < 4; ks++)
        xa[ks] = ld8_f32_bf16(x + (size_t)(tok0 + l16) * D + ks * 32 + quad * 8);

    __syncthreads();

    bf16* __restrict__ T = Scr[w];

    if (phase < 2) {
        // ---- Q or K: A = x, B = W fragment ----
        bf16* __restrict__ outp = (phase == 0) ? qf : kf;
        const float scale = (phase == 0) ? QSCALE : 1.0f;
#pragma unroll
        for (int nt = 0; nt < 8; nt++) {
            f32x4 acc = {0.f, 0.f, 0.f, 0.f};
#pragma unroll
            for (int ks = 0; ks < 4; ks++) {
                bf16x8 bw = *(const bf16x8*)&Wl[((nt * 4 + ks) * 64 + lane) * 8];
                acc = MFMA16(xa[ks], bw, acc);
            }
            // C: row = token = quad*4+rg, col = n = nt*16+l16
#pragma unroll
            for (int rg = 0; rg < 4; rg++)
                T[(quad * 4 + rg) * 136 + nt * 16 + l16] = (bf16)(acc[rg] * scale);
        }
        // readback fragments (tok = l16), coalesced 1KB stores
#pragma unroll
        for (int ks = 0; ks < 4; ks++) {
            bf16x8 frag = *(const bf16x8*)&T[l16 * 136 + ks * 32 + quad * 8];
            *(bf16x8*)(outp + (((size_t)tile * 4 + ks) * 64 + lane) * 8) = frag;
        }
    } else {
        // ---- V: A = Wv fragment (row = o), B = x (col = token) ----
#pragma unroll
        for (int mt = 0; mt < 8; mt++) {
            f32x4 acc = {0.f, 0.f, 0.f, 0.f};
#pragma unroll
            for (int ks = 0; ks < 4; ks++) {
                bf16x8 aw = *(const bf16x8*)&Wl[((mt * 4 + ks) * 64 + lane) * 8];
                acc = MFMA16(aw, xa[ks], acc);
            }
            // C: row = o = mt*16+quad*4+rg, col = token = l16  ->  T[o][tok]
#pragma unroll
            for (int rg = 0; rg < 4; rg++)
                T[(mt * 16 + quad * 4 + rg) * 20 + l16] = (bf16)acc[rg];
        }
        const int g64 = tok0 >> 6;
        const int t4 = (tok0 >> 4) & 3;
        const int m = t4 >> 1;
        const int jh = t4 & 1;
#pragma unroll
        for (int ot = 0; ot < 8; ot++) {
            bf16x4 v4 = *(const bf16x4*)&T[(ot * 16 + l16) * 20 + quad * 4];
            *(bf16x4*)(vf + ((((size_t)g64 * 8 + ot) * 2 + m) * 64 + lane) * 8 +
                       jh * 4) = v4;
        }
    }
}

// ---------------------------------------------------------------------------
// flash: grid 256 x 512 (8 waves, 1 block/CU). Wave w -> (pair p = w&3,
// u = w>>2). Pair p owns keys [p*1024, +1024) in 8 iters of 128 (two 64-key
// sub-groups A,B per iter); wave (p,u) owns q-tiles qtg0+2u, +1. K: per-pair
// single-buffered 32KB LDS (32 units; wave u fills units u*16..u*16+15) via
// global_load_lds (fill after reads-barrier, landed by end-of-iter barrier);
// V: global->regs, one group live at a time. Rowsum: scalar adds + shfl.
// End: 4-split combine through reused LDS.
// ---------------------------------------------------------------------------
__global__ __launch_bounds__(512) __attribute__((amdgpu_waves_per_eu(2, 2)))
void flash(const bf16* __restrict__ qf,
           const bf16* __restrict__ kf,
           const bf16* __restrict__ vf,
           float* __restrict__ out) {
    // loop: kbuf[pair][32KB]; epilogue: float Rs[12][2368] + RsS[16][16]
    __shared__ __attribute__((aligned(16))) bf16 kbuf[4][16384];  // 128 KB

    const int lane = threadIdx.x & 63;
    const int w = threadIdx.x >> 6;
    const int p = w & 3;    // key-quarter
    const int u = w >> 2;   // q-half within block
    const int l16 = lane & 15;
    const int quad = lane >> 4;

    // XCD swizzle: bid%8 -> (batch, sub); 2 XCDs per batch.
    const int lo = blockIdx.x & 7;
    const int batch = lo >> 1;
    const int sub = lo & 1;
    const int qg = (int)(blockIdx.x >> 3) * 2 + sub;  // 0..63
    const int qtg0 = batch * 256 + qg * 4;

    bf16x8 aq[2][4];
#pragma unroll
    for (int j = 0; j < 2; j++)
#pragma unroll
        for (int ks = 0; ks < 4; ks++)
            aq[j][ks] = *(const bf16x8*)(qf +
                (((size_t)(qtg0 + 2 * u + j) * 4 + ks) * 64 + lane) * 8);

    f32x4 oacc[2][8];
#pragma unroll
    for (int j = 0; j < 2; j++)
#pragma unroll
        for (int i = 0; i < 8; i++) oacc[j][i] = (f32x4){0.f, 0.f, 0.f, 0.f};
    float rs[2] = {0.f, 0.f};

    const int kb0 = p * 1024;
    const size_t kfb = (size_t)(batch * 256) * 2048;  // batch base in kf
    bf16* __restrict__ kp = &kbuf[p][0];

    // ---- prologue: fill tile 0 (32 KB = 32 units; wave u does 16) ----
    {
        const size_t kt0 = kfb + (size_t)(kb0 >> 4) * 2048;
#pragma unroll
        for (int c = 0; c < 16; c++) {
            const int unit = u * 16 + c;
            g2lds16(kf + kt0 + unit * 512 + lane * 8, kp + unit * 512);
        }
    }
    __syncthreads();

#pragma unroll 1
    for (int t = 0; t < 8; t++) {
        const int kb = kb0 + t * 128;
        const size_t g64A = (size_t)batch * 64 + (kb >> 6);
        const size_t g64B = g64A + 1;

        // ================= sub-group A (keys kb..kb+63) =================
        bf16x8 bvA1[4][2];
#pragma unroll
        for (int ot = 0; ot < 4; ot++)
#pragma unroll
            for (int m = 0; m < 2; m++)
                bvA1[ot][m] = *(const bf16x8*)(vf +
                    (((g64A * 8 + ot) * 2 + m) * 64 + lane) * 8);
        SB0();

        f32x4 sv[2][4];
#pragma unroll
        for (int j = 0; j < 2; j++)
#pragma unroll
            for (int nt = 0; nt < 4; nt++) sv[j][nt] = (f32x4){0.f, 0.f, 0.f, 0.f};
        __builtin_amdgcn_s_setprio(1);
#pragma unroll
        for (int ks = 0; ks < 4; ks++)
#pragma unroll
            for (int nt = 0; nt < 4; nt++) {
                bf16x8 bk = *(const bf16x8*)(kp + (nt * 4 + ks) * 512 + lane * 8);
                sv[0][nt] = MFMA16(bk, aq[0][ks], sv[0][nt]);
                sv[1][nt] = MFMA16(bk, aq[1][ks], sv[1][nt]);
            }
        __builtin_amdgcn_s_setprio(0);
        SB0();

        bf16x8 bvA2[4][2];
#pragma unroll
        for (int ot = 0; ot < 4; ot++)
#pragma unroll
            for (int m = 0; m < 2; m++)
                bvA2[ot][m] = *(const bf16x8*)(vf +
                    (((g64A * 8 + ot + 4) * 2 + m) * 64 + lane) * 8);
        SB0();

        bf16x8 ap[2][2];
#pragma unroll
        for (int j = 0; j < 2; j++)
#pragma unroll
            for (int m = 0; m < 2; m++) {
                bf16x8 tt;
#pragma unroll
                for (int e = 0; e < 4; e++) {
                    tt[e] = (bf16)EXP2F(sv[j][2 * m][e]);
                    tt[e + 4] = (bf16)EXP2F(sv[j][2 * m + 1][e]);
                    rs[j] += (float)tt[e] + (float)tt[e + 4];
                }
                ap[j][m] = tt;
            }
        SB0();

        __builtin_amdgcn_s_setprio(1);
#pragma unroll
        for (int ot = 0; ot < 4; ot++)
#pragma unroll
            for (int m = 0; m < 2; m++) {
                oacc[0][ot] = MFMA16(ap[0][m], bvA1[ot][m], oacc[0][ot]);
                oacc[1][ot] = MFMA16(ap[1][m], bvA1[ot][m], oacc[1][ot]);
            }
#pragma unroll
        for (int ot = 0; ot < 4; ot++)
#pragma unroll
            for (int m = 0; m < 2; m++) {
                oacc[0][ot + 4] = MFMA16(ap[0][m], bvA2[ot][m], oacc[0][ot + 4]);
                oacc[1][ot + 4] = MFMA16(ap[1][m], bvA2[ot][m], oacc[1][ot + 4]);
            }
        __builtin_amdgcn_s_setprio(0);
        SB0();

        // ================= sub-group B (keys kb+64..kb+127) =================
        bf16x8 bvB1[4][2];
#pragma unroll
        for (int ot = 0; ot < 4; ot++)
#pragma unroll
            for (int m = 0; m < 2; m++)
                bvB1[ot][m] = *(const bf16x8*)(vf +
                    (((g64B * 8 + ot) * 2 + m) * 64 + lane) * 8);
        SB0();

#pragma unroll
        for (int j = 0; j < 2; j++)
#pragma unroll
            for (int nt = 0; nt < 4; nt++) sv[j][nt] = (f32x4){0.f, 0.f, 0.f, 0.f};
        __builtin_amdgcn_s_setprio(1);
#pragma unroll
        for (int ks = 0; ks < 4; ks++)
#pragma unroll
            for (int nt = 0; nt < 4; nt++) {
                bf16x8 bk = *(const bf16x8*)(kp + 8192 + (nt * 4 + ks) * 512 +
                                             lane * 8);
                sv[0][nt] = MFMA16(bk, aq[0][ks], sv[0][nt]);
                sv[1][nt] = MFMA16(bk, aq[1][ks], sv[1][nt]);
            }
        __builtin_amdgcn_s_setprio(0);
        SB0();

        bf16x8 bvB2[4][2];
#pragma unroll
        for (int ot = 0; ot < 4; ot++)
#pragma unroll
            for (int m = 0; m < 2; m++)
                bvB2[ot][m] = *(const bf16x8*)(vf +
                    (((g64B * 8 + ot + 4) * 2 + m) * 64 + lane) * 8);
        SB0();

#pragma unroll
        for (int j = 0; j < 2; j++)
#pragma unroll
            for (int m = 0; m < 2; m++) {
                bf16x8 tt;
#pragma unroll
                for (int e = 0; e < 4; e++) {
                    tt[e] = (bf16)EXP2F(sv[j][2 * m][e]);
                    tt[e + 4] = (bf16)EXP2F(sv[j][2 * m + 1][e]);
                    rs[j] += (float)tt[e] + (float)tt[e + 4];
                }
                ap[j][m] = tt;
            }

        // all kbuf reads of tile t done (A and B QK both issued above)
        __syncthreads();

        // ---- fill tile t+1 (async; landed by end-of-iter barrier) ----
        if (t < 7) {
            const size_t ktn = kfb + (size_t)((kb0 + (t + 1) * 128) >> 4) * 2048;
#pragma unroll
            for (int c = 0; c < 16; c++) {
                const int unit = u * 16 + c;
                g2lds16(kf + ktn + unit * 512 + lane * 8, kp + unit * 512);
            }
        }
        SB0();

        __builtin_amdgcn_s_setprio(1);
#pragma unroll
        for (int ot = 0; ot < 4; ot++)
#pragma unroll
            for (int m = 0; m < 2; m++) {
                oacc[0][ot] = MFMA16(ap[0][m], bvB1[ot][m], oacc[0][ot]);
                oacc[1][ot] = MFMA16(ap[1][m], bvB1[ot][m], oacc[1][ot]);
            }
#pragma unroll
        for (int ot = 0; ot < 4; ot++)
#pragma unroll
            for (int m = 0; m < 2; m++) {
                oacc[0][ot + 4] = MFMA16(ap[0][m], bvB2[ot][m], oacc[0][ot + 4]);
                oacc[1][ot + 4] = MFMA16(ap[1][m], bvB2[ot][m], oacc[1][ot + 4]);
            }
        __builtin_amdgcn_s_setprio(0);

        if (t < 7) __syncthreads();  // fill landed; safe to read next tile
    }

    // ---- rowsum: each lane -> total for row l16 ----
#pragma unroll
    for (int j = 0; j < 2; j++) {
        rs[j] += __shfl_xor(rs[j], 16);
        rs[j] += __shfl_xor(rs[j], 32);
    }

    // ---- 4-split combine through reused LDS ----
    float* __restrict__ Rs = (float*)kbuf;          // 12 x 2368 floats
    float* __restrict__ RsS = Rs + 12 * 2368;       // 16 x 16 floats
    __syncthreads();  // everyone past last kbuf read
#pragma unroll
    for (int j = 0; j < 2; j++) {
        if (quad == 0) RsS[(p * 4 + u * 2 + j) * 16 + l16] = rs[j];
        if (p > 0) {
            float* __restrict__ dst = Rs + ((p - 1) * 4 + u * 2 + j) * 2368;
#pragma unroll
            for (int tt = 0; tt < 8; tt++)
#pragma unroll
                for (int rg = 0; rg < 4; rg++)
                    dst[(quad * 4 + rg) * 148 + tt * 16 + l16] = oacc[j][tt][rg];
        }
    }
    __syncthreads();
    if (p == 0) {
#pragma unroll
        for (int j = 0; j < 2; j++) {
#pragma unroll
            for (int sIdx = 0; sIdx < 3; sIdx++) {
                const float* __restrict__ src = Rs + (sIdx * 4 + u * 2 + j) * 2368;
#pragma unroll
                for (int tt = 0; tt < 8; tt++)
#pragma unroll
                    for (int rg = 0; rg < 4; rg++)
                        oacc[j][tt][rg] += src[(quad * 4 + rg) * 148 + tt * 16 + l16];
            }
#pragma unroll
            for (int rg = 0; rg < 4; rg++) {
                const int row = quad * 4 + rg;
                float den = 0.f;
#pragma unroll
                for (int sp = 0; sp < 4; sp++)
                    den += RsS[(sp * 4 + u * 2 + j) * 16 + row];
                const float rl = 1.0f / den;
                float* __restrict__ yrow = out +
                    (((size_t)(qtg0 + 2 * u + j)) * 16 + row) * D;
#pragma unroll
                for (int tt = 0; tt < 8; tt++)
                    yrow[tt * 16 + l16] = oacc[j][tt][rg] * rl;
            }
        }
    }
}

// ---------------------------------------------------------------------------
extern "C" void kernel_launch(void* const* d_in, const int* in_sizes, int n_in,
                              void* d_out, int out_size, void* d_ws, size_t ws_size,
                              hipStream_t stream) {
    const float* x = (const float*)d_in[0];
    const float* Wq = (const float*)d_in[1];
    const float* Wk = (const float*)d_in[2];
    const float* Wv = (const float*)d_in[3];
    float* y = (float*)d_out;

    bf16* qf = (bf16*)d_ws;            // 4MB
    bf16* kf = qf + (size_t)ROWS * D;  // 4MB
    bf16* vf = kf + (size_t)ROWS * D;  // 4MB (kappa-permuted fragment layout)

    proj_all<<<768, 256, 0, stream>>>(x, Wq, Wk, Wv, qf, kf, vf);
    flash<<<256, 512, 0, stream>>>(qf, kf, vf, y);
}